// Round 8
// baseline (115.634 us; speedup 1.0000x reference)
//
#include <hip/hip_runtime.h>
#include <hip/hip_fp16.h>
#include <math.h>

// B=4, C=64, H=W=128, O=64, K=3, pad=1, stride=1
// Round-21: R17 (green, 97.2us) + ONE structural delta: DELETE the NCHW->NHWC
// transpose kernel and the xh intermediate. k_fused phase 0 now stages the 20x13
// halo directly from NCHW fp32 x (f32->f16 RNE at LDS-write time; values bit-identical
// to the old xh path). Rare out-of-patch fallback reads x scalar (cold).
// Remaining prep = tiny 216-block weight pack. Traffic: 42MB -> 34MB; removes the
// 2048-block dispatch + most of the prep->fused boundary.
// R20's cooperative grid.sync FAILED correctness (stale xh cross-XCD) - abandoned.
// Phases 1/2, LDS layouts, MFMA structure verbatim from R17.
// Known harness floor (268MB ws re-poison fill @ ~6TB/s + restores) is inside dur_us.
// ws: wtF + pgwF (~110 KB)

typedef __attribute__((ext_vector_type(8))) short short8;     // 8 f16 bit-patterns (A/B frag)
typedef __attribute__((ext_vector_type(8))) _Float16 f16x8;   // MFMA A/B frag (4 VGPRs)
typedef __attribute__((ext_vector_type(4))) float f32x4;      // C/D frag

#define PSTR 2088   // padded plane stride in shorts (260 pos * 8 ch + 8 pad)

__device__ __forceinline__ unsigned short f2h(float f) {   // RNE f32->f16
    union { __half h; unsigned short s; } v; v.h = __float2half_rn(f); return v.s;
}
__device__ __forceinline__ f16x8 s2f(short8 s) {
    union { short8 s; f16x8 f; } u; u.s = s; return u.f;
}
__device__ __forceinline__ __half2 u2h2(unsigned u) {
    union { unsigned u; __half2 h; } v; v.u = u; return v.h;
}
__device__ __forceinline__ unsigned h22u(__half2 h) {
    union { __half2 h; unsigned u; } v; v.h = h; return v.u;
}
__device__ __forceinline__ unsigned uget(const uint4& v, int p) {
    return p == 0 ? v.x : p == 1 ? v.y : p == 2 ? v.z : v.w;
}

// ---------------- K1: pack weights to f16, FRAGMENT order (exact R17 pack body) ----------------
__global__ __launch_bounds__(256) void k_pack(const float* __restrict__ weight,
                                              const float* __restrict__ pg_w,
                                              unsigned short* __restrict__ wtF,
                                              unsigned short* __restrict__ pgwF) {
    int idx = blockIdx.x * 256 + threadIdx.x;
    if (idx < 36864) {
        int e = idx & 7, l = (idx >> 3) & 63, grp = idx >> 9;   // grp 0..71
        int nt = grp & 3, kb = (grp >> 2) & 1, kk = grp >> 3;
        int ln = l & 15, quad = l >> 4;
        int o = nt * 16 + ln;
        int c = kb * 32 + quad * 8 + e;
        wtF[idx] = f2h(weight[(o * 64 + c) * 9 + kk]);
    }
    int i2 = idx - 36864;
    if (i2 >= 0 && i2 < 18432) {
        int e = i2 & 7, l = (i2 >> 3) & 63, grp = i2 >> 9;      // grp 0..35
        int tl = grp & 1, kb = grp >> 1;
        int ln = l & 15, quad = l >> 4;
        int p = tl * 16 + ln;
        int k = kb * 32 + quad * 8 + e;
        float v = 0.f;
        if (p < 27) {
            int q = k >> 6, c = k & 63;
            v = pg_w[(p * 64 + c) * 9 + q];
        }
        pgwF[i2] = f2h(v);
    }
}

// ---------------- K2: fused offset-conv + deformable conv, 8x16 tile ----------------
// 512 blocks (b x 16 x 8), tile = 8 rows x 16 cols. 512 threads = 8 waves; wave w = row w.
__global__ __launch_bounds__(512) void k_fused(const float* __restrict__ x,
                                               const unsigned short* __restrict__ pgwF,
                                               const float* __restrict__ pg_b,
                                               const unsigned short* __restrict__ wtF,
                                               const float* __restrict__ bias,
                                               float* __restrict__ out) {
    __shared__ unsigned short patch[8 * PSTR];   // 32.6 KB [cg][pos][8ch], plane pad +8
    __shared__ float P_s[27 * 129];              // 13.9 KB [param][px], stride 129

    int bid = blockIdx.x;
    int b  = bid >> 7;
    int h0 = ((bid >> 3) & 15) * 8;
    int w0 = (bid & 7) * 16;
    int t = threadIdx.x;
    int base_y = h0 - 2, base_x = w0 - 2;
    const float* xb0 = x + (size_t)b * 64 * 16384;   // NCHW batch base

    // ---- phase 0: stage 20x13 halo direct from NCHW fp32 x; f32->f16 RNE here ----
    // item = (channel-pair cp 0..31) x (yy 0..12) x (xx 0..19): 8320 items.
    // lanes walk xx => coalesced 80B segments; LDS write = one u32 (2 packed f16).
    for (int i = t; i < 8320; i += 512) {
        int cp  = i / 260;
        int rem = i - cp * 260;
        int yy  = rem / 20;
        int xx  = rem - yy * 20;
        int gy = base_y + yy, gx = base_x + xx;
        unsigned u = 0;
        if (((unsigned)gy < 128u) && ((unsigned)gx < 128u)) {
            int c = cp * 2;
            float f0 = xb0[(c * 128 + gy) * 128 + gx];
            float f1 = xb0[((c + 1) * 128 + gy) * 128 + gx];
            u = (unsigned)f2h(f0) | ((unsigned)f2h(f1) << 16);
        }
        int pos = yy * 20 + xx;
        *(unsigned*)&patch[(cp >> 2) * PSTR + pos * 8 + (cp & 3) * 2] = u;
    }
    __syncthreads();

    int l = t & 63, w = t >> 6;          // w = 0..7 = pixel row
    int quad = l >> 4, ln = l & 15;
    int px = w * 16 + ln;                // px = row-major pixel id (row w, col ln)
    int hh = h0 + w, ww = w0 + ln;

    // ---- phase 1: offset conv MFMA (M=128, N=32, K=576), B from pgwF coalesced ----
    {
        f32x4 o0 = {0.f, 0.f, 0.f, 0.f}, o1 = {0.f, 0.f, 0.f, 0.f};
#pragma unroll
        for (int kb = 0; kb < 18; ++kb) {
            int q = kb >> 1;
            int kh = q / 3, kw = q - 3 * (q / 3);
            short8 b0 = *(const short8*)&pgwF[(kb * 2 + 0) * 512 + l * 8];   // lane*16B
            short8 b1 = *(const short8*)&pgwF[(kb * 2 + 1) * 512 + l * 8];
            int aoff = (w + kh + 1) * 20 + (ln + kw + 1);
            int cg = (kb & 1) * 4 + quad;
            short8 af = *(const short8*)&patch[cg * PSTR + aoff * 8];
            o0 = __builtin_amdgcn_mfma_f32_16x16x32_f16(s2f(af), s2f(b0), o0, 0, 0, 0);
            o1 = __builtin_amdgcn_mfma_f32_16x16x32_f16(s2f(af), s2f(b1), o1, 0, 0, 0);
        }
#pragma unroll
        for (int tile = 0; tile < 2; ++tile) {
            int p = tile * 16 + ln;
            f32x4 a = tile ? o1 : o0;
            if (p < 27) {
                float bo = pg_b[p];
#pragma unroll
                for (int i = 0; i < 4; ++i) {
                    int wpx = w * 16 + quad * 4 + i;
                    float v = a[i] + bo;
                    if (p >= 18) v = 1.f / (1.f + expf(-v));
                    P_s[p * 129 + wpx] = v;
                }
            }
        }
    }
    __syncthreads();

    // ---- phase 2: sampling + main GEMM (M=128,N=64,K=576), B from wtF coalesced ----
    f32x4 acc[4];
#pragma unroll
    for (int nt = 0; nt < 4; ++nt) acc[nt] = (f32x4){0.f, 0.f, 0.f, 0.f};

    int qbase = quad * PSTR;             // per-thread constant plane base

    for (int kk = 0; kk < 9; ++kk) {
        // B fragments: coalesced lane*16B loads (L1/L2-hot)
        short8 bfr[2][4];
#pragma unroll
        for (int kb = 0; kb < 2; ++kb)
#pragma unroll
            for (int nt = 0; nt < 4; ++nt)
                bfr[kb][nt] = *(const short8*)&wtF[((kk * 2 + kb) * 4 + nt) * 512 + l * 8];

        // bilinear params from LDS (stride 129)
        int ki = kk / 3, kj = kk - 3 * (kk / 3);
        float dyv = P_s[(2 * kk) * 129 + px];
        float dxv = P_s[(2 * kk + 1) * 129 + px];
        float m   = P_s[(18 + kk) * 129 + px];
        float ys = (float)(hh - 1 + ki) + dyv;
        float xs = (float)(ww - 1 + kj) + dxv;
        float y0f = floorf(ys), x0f = floorf(xs);
        int y0 = (int)y0f, x0 = (int)x0f;
        float ly = ys - y0f, lx = xs - x0f;
        float v0y = ((unsigned)y0 < 128u) ? 1.f : 0.f;
        float v1y = ((unsigned)(y0 + 1) < 128u) ? 1.f : 0.f;
        float v0x = ((unsigned)x0 < 128u) ? 1.f : 0.f;
        float v1x = ((unsigned)(x0 + 1) < 128u) ? 1.f : 0.f;
        float w00 = (1.f - ly) * (1.f - lx) * v0y * v0x * m;
        float w01 = (1.f - ly) * lx * v0y * v1x * m;
        float w10 = ly * (1.f - lx) * v1y * v0x * m;
        float w11 = ly * lx * v1y * v1x * m;
        int ly0 = y0 - base_y, lx0 = x0 - base_x;
        bool inp = ((unsigned)ly0 < 12u) && ((unsigned)lx0 < 18u);

        uint4 r[2][4];
        if (inp) {
            int pb = qbase + (ly0 * 20 + lx0) * 8;   // one base; corners = imm offsets
#pragma unroll
            for (int kb = 0; kb < 2; ++kb) {
                int base = pb + kb * 4 * PSTR;       // kb term folds to imm in ds_read
                r[kb][0] = *(const uint4*)&patch[base];
                r[kb][1] = *(const uint4*)&patch[base + 8];
                r[kb][2] = *(const uint4*)&patch[base + 160];
                r[kb][3] = *(const uint4*)&patch[base + 168];
            }
        } else {   // rare (|offset| >= 1): direct NCHW fp32 reads, clamped corners, same RNE
            int y0c = min(max(y0, 0), 127), y1c = min(max(y0 + 1, 0), 127);
            int x0c = min(max(x0, 0), 127), x1c = min(max(x0 + 1, 0), 127);
            int yc[4] = {y0c, y0c, y1c, y1c};
            int xc[4] = {x0c, x1c, x0c, x1c};
#pragma unroll
            for (int kb = 0; kb < 2; ++kb) {
                int c0 = kb * 32 + quad * 8;
#pragma unroll
                for (int cr = 0; cr < 4; ++cr) {
                    union { unsigned u[4]; uint4 v; } tmp;
#pragma unroll
                    for (int e = 0; e < 4; ++e) {
                        float f0 = xb0[((c0 + 2 * e) * 128 + yc[cr]) * 128 + xc[cr]];
                        float f1 = xb0[((c0 + 2 * e + 1) * 128 + yc[cr]) * 128 + xc[cr]];
                        tmp.u[e] = (unsigned)f2h(f0) | ((unsigned)f2h(f1) << 16);
                    }
                    r[kb][cr] = tmp.v;
                }
            }
        }

        // packed-f16 bilinear: 2 channels per step; pure v_pk_mul/fma_f16, no unpack/repack
        __half2 W00 = __float2half2_rn(w00), W01 = __float2half2_rn(w01);
        __half2 W10 = __float2half2_rn(w10), W11 = __float2half2_rn(w11);
        f16x8 af[2];
#pragma unroll
        for (int kb = 0; kb < 2; ++kb) {
            union { unsigned u[4]; f16x8 f; } afu;
#pragma unroll
            for (int p = 0; p < 4; ++p) {
                __half2 v = __hmul2(W00, u2h2(uget(r[kb][0], p)));
                v = __hfma2(W01, u2h2(uget(r[kb][1], p)), v);
                v = __hfma2(W10, u2h2(uget(r[kb][2], p)), v);
                v = __hfma2(W11, u2h2(uget(r[kb][3], p)), v);
                afu.u[p] = h22u(v);
            }
            af[kb] = afu.f;
        }

#pragma unroll
        for (int kb = 0; kb < 2; ++kb)
#pragma unroll
            for (int nt = 0; nt < 4; ++nt)
                acc[nt] = __builtin_amdgcn_mfma_f32_16x16x32_f16(af[kb], s2f(bfr[kb][nt]), acc[nt], 0, 0, 0);
    }

    // ---- epilogue: lane's 4 D-rows per nt = row w, cols quad*4..+3 -> float4 ----
    int ehh = h0 + w, eww = w0 + quad * 4;
#pragma unroll
    for (int nt = 0; nt < 4; ++nt) {
        int o = nt * 16 + ln;
        float bo = bias[o];
        float4 v;
        v.x = acc[nt][0] + bo; v.y = acc[nt][1] + bo;
        v.z = acc[nt][2] + bo; v.w = acc[nt][3] + bo;
        *(float4*)&out[((size_t)b * 64 + o) * 16384 + ehh * 128 + eww] = v;
    }
}

extern "C" void kernel_launch(void* const* d_in, const int* in_sizes, int n_in,
                              void* d_out, int out_size, void* d_ws, size_t ws_size,
                              hipStream_t stream) {
    const float* x      = (const float*)d_in[0];
    const float* weight = (const float*)d_in[1];
    const float* bias   = (const float*)d_in[2];
    const float* pg_w   = (const float*)d_in[3];
    const float* pg_b   = (const float*)d_in[4];
    float* out = (float*)d_out;

    unsigned short* wtF  = (unsigned short*)d_ws;   // 36,864 f16 (fragment order)
    unsigned short* pgwF = wtF + 36864;             // 18,432 f16 (fragment order)

    k_pack<<<216, 256, 0, stream>>>(weight, pg_w, wtF, pgwF);
    k_fused<<<512, 512, 0, stream>>>(x, pgwF, pg_b, wtF, bias, out);
}

// Round 10
// 98.504 us; speedup vs baseline: 1.1739x; 1.1739x over previous
//
#include <hip/hip_runtime.h>
#include <hip/hip_fp16.h>
#include <math.h>

// B=4, C=64, H=W=128, O=64, K=3, pad=1, stride=1
// Round-23: RESUBMIT of R22 (container infra failure, no measurement taken).
// R22 = R17 structure (green 97.2us) + ONE delta: BRANCHLESS common-path corner
// reads in phase 2. The old if(inp){LDS}else{global} divergent branch pinned the
// 8 corner ds_reads behind a branch selecting address spaces -> compiler could not
// hoist/pipeline them (why R18's unroll was neutral). Now: always ds_read at
// clamped in-patch base, then rare wave-uniform fixup (__any(!inp)) overwrites from
// global. + #pragma unroll on kk so the scheduler overlaps iteration k+1's
// P_s/addr/ds_reads under iteration k's cvt+MFMA.
// R21's counters showed k_fused ~44-49us, all pipes <30% busy => latency-bound.
// Known harness floor ~52us (268MB ws re-poison fill @ ~6TB/s + restores) is inside dur_us.
// ws: xh 8.39 MB + wtF + pgwF (~8.5 MB)

typedef __attribute__((ext_vector_type(8))) short short8;     // 8 f16 bit-patterns (A/B frag)
typedef __attribute__((ext_vector_type(8))) _Float16 f16x8;   // MFMA A/B frag (4 VGPRs)
typedef __attribute__((ext_vector_type(4))) float f32x4;      // C/D frag

#define PSTR 2088   // padded plane stride in shorts (260 pos * 8 ch + 8 pad)

__device__ __forceinline__ unsigned short f2h(float f) {   // RNE f32->f16
    union { __half h; unsigned short s; } v; v.h = __float2half_rn(f); return v.s;
}
__device__ __forceinline__ f16x8 s2f(short8 s) {
    union { short8 s; f16x8 f; } u; u.s = s; return u.f;
}
__device__ __forceinline__ __half2 u2h2(unsigned u) {
    union { unsigned u; __half2 h; } v; v.u = u; return v.h;
}
__device__ __forceinline__ unsigned h22u(__half2 h) {
    union { __half2 h; unsigned u; } v; v.h = h; return v.u;
}
__device__ __forceinline__ unsigned uget(const uint4& v, int p) {
    return p == 0 ? v.x : p == 1 ? v.y : p == 2 ? v.z : v.w;
}

// ---------------- K0: merged prep: NCHW->NHWC f16 transpose  +  weight pack (exact R17) ----------------
__global__ __launch_bounds__(256) void k_prep(const float* __restrict__ x,
                                              unsigned short* __restrict__ xh,
                                              const float* __restrict__ weight,
                                              const float* __restrict__ pg_w,
                                              unsigned short* __restrict__ wtF,
                                              unsigned short* __restrict__ pgwF) {
    __shared__ float tile[64][33];
    int bid = blockIdx.x;
    int t = threadIdx.x;
    if (bid < 2048) {
        int b = bid >> 9, h = (bid >> 2) & 127, w0 = (bid & 3) * 32;
        for (int idx = t; idx < 2048; idx += 256) {
            int c = idx >> 5, w = idx & 31;
            tile[c][w] = x[((b * 64 + c) * 128 + h) * 128 + w0 + w];
        }
        __syncthreads();
        {
            int wl = t >> 3, c0 = (t & 7) * 8;
            short8 v;
#pragma unroll
            for (int e = 0; e < 8; ++e) v[e] = (short)f2h(tile[c0 + e][wl]);
            *(short8*)&xh[(((size_t)b * 128 + h) * 128 + w0 + wl) * 64 + c0] = v;
        }
    } else {
        int idx = (bid - 2048) * 256 + t;
        if (idx < 36864) {
            int e = idx & 7, l = (idx >> 3) & 63, grp = idx >> 9;   // grp 0..71
            int nt = grp & 3, kb = (grp >> 2) & 1, kk = grp >> 3;
            int ln = l & 15, quad = l >> 4;
            int o = nt * 16 + ln;
            int c = kb * 32 + quad * 8 + e;
            wtF[idx] = f2h(weight[(o * 64 + c) * 9 + kk]);
        }
        int i2 = idx - 36864;
        if (i2 >= 0 && i2 < 18432) {
            int e = i2 & 7, l = (i2 >> 3) & 63, grp = i2 >> 9;      // grp 0..35
            int tl = grp & 1, kb = grp >> 1;
            int ln = l & 15, quad = l >> 4;
            int p = tl * 16 + ln;
            int k = kb * 32 + quad * 8 + e;
            float v = 0.f;
            if (p < 27) {
                int q = k >> 6, c = k & 63;
                v = pg_w[(p * 64 + c) * 9 + q];
            }
            pgwF[i2] = f2h(v);
        }
    }
}

// ---------------- K2: fused offset-conv + deformable conv, 8x16 tile ----------------
// 512 blocks (b x 16 x 8), tile = 8 rows x 16 cols. 512 threads = 8 waves; wave w = row w.
__global__ __launch_bounds__(512) void k_fused(const unsigned short* __restrict__ xh,
                                               const unsigned short* __restrict__ pgwF,
                                               const float* __restrict__ pg_b,
                                               const unsigned short* __restrict__ wtF,
                                               const float* __restrict__ bias,
                                               float* __restrict__ out) {
    __shared__ unsigned short patch[8 * PSTR];   // 32.6 KB [cg][pos][8ch], plane pad +8
    __shared__ float P_s[27 * 129];              // 13.9 KB [param][px], stride 129

    int bid = blockIdx.x;
    int b  = bid >> 7;
    int h0 = ((bid >> 3) & 15) * 8;
    int w0 = (bid & 7) * 16;
    int t = threadIdx.x;
    int base_y = h0 - 2, base_x = w0 - 2;
    const unsigned short* xbb = xh + (size_t)b * 16384 * 64;

    // ---- phase 0: stage patch from xh; 2080 b128 chunks, coalesced ----
    for (int i = t; i < 2080; i += 512) {
        int yy = i / 160;                 // 8 chunks per 20-col row
        int r  = i - yy * 160;
        int xx = r >> 3;
        int cg = r & 7;
        int gy = base_y + yy, gx = base_x + xx;
        int pos = yy * 20 + xx;
        short8 v = (short8)0;
        if (((unsigned)gy < 128u) && ((unsigned)gx < 128u))
            v = *(const short8*)&xbb[(gy * 128 + gx) * 64 + cg * 8];
        *(short8*)&patch[cg * PSTR + pos * 8] = v;
    }
    __syncthreads();

    int l = t & 63, w = t >> 6;          // w = 0..7 = pixel row
    int quad = l >> 4, ln = l & 15;
    int px = w * 16 + ln;                // px = row-major pixel id (row w, col ln)
    int hh = h0 + w, ww = w0 + ln;

    // ---- phase 1: offset conv MFMA (M=128, N=32, K=576), B from pgwF coalesced ----
    {
        f32x4 o0 = {0.f, 0.f, 0.f, 0.f}, o1 = {0.f, 0.f, 0.f, 0.f};
#pragma unroll
        for (int kb = 0; kb < 18; ++kb) {
            int q = kb >> 1;
            int kh = q / 3, kw = q - 3 * (q / 3);
            short8 b0 = *(const short8*)&pgwF[(kb * 2 + 0) * 512 + l * 8];   // lane*16B
            short8 b1 = *(const short8*)&pgwF[(kb * 2 + 1) * 512 + l * 8];
            int aoff = (w + kh + 1) * 20 + (ln + kw + 1);
            int cg = (kb & 1) * 4 + quad;
            short8 af = *(const short8*)&patch[cg * PSTR + aoff * 8];
            o0 = __builtin_amdgcn_mfma_f32_16x16x32_f16(s2f(af), s2f(b0), o0, 0, 0, 0);
            o1 = __builtin_amdgcn_mfma_f32_16x16x32_f16(s2f(af), s2f(b1), o1, 0, 0, 0);
        }
#pragma unroll
        for (int tile = 0; tile < 2; ++tile) {
            int p = tile * 16 + ln;
            f32x4 a = tile ? o1 : o0;
            if (p < 27) {
                float bo = pg_b[p];
#pragma unroll
                for (int i = 0; i < 4; ++i) {
                    int wpx = w * 16 + quad * 4 + i;
                    float v = a[i] + bo;
                    if (p >= 18) v = 1.f / (1.f + expf(-v));
                    P_s[p * 129 + wpx] = v;
                }
            }
        }
    }
    __syncthreads();

    // ---- phase 2: sampling + main GEMM (M=128,N=64,K=576), B from wtF coalesced ----
    f32x4 acc[4];
#pragma unroll
    for (int nt = 0; nt < 4; ++nt) acc[nt] = (f32x4){0.f, 0.f, 0.f, 0.f};

    int qbase = quad * PSTR;             // per-thread constant plane base

#pragma unroll
    for (int kk = 0; kk < 9; ++kk) {
        // B fragments: coalesced lane*16B loads (L1/L2-hot)
        short8 bfr[2][4];
#pragma unroll
        for (int kb = 0; kb < 2; ++kb)
#pragma unroll
            for (int nt = 0; nt < 4; ++nt)
                bfr[kb][nt] = *(const short8*)&wtF[((kk * 2 + kb) * 4 + nt) * 512 + l * 8];

        // bilinear params from LDS (stride 129)
        int ki = kk / 3, kj = kk - 3 * (kk / 3);
        float dyv = P_s[(2 * kk) * 129 + px];
        float dxv = P_s[(2 * kk + 1) * 129 + px];
        float m   = P_s[(18 + kk) * 129 + px];
        float ys = (float)(hh - 1 + ki) + dyv;
        float xs = (float)(ww - 1 + kj) + dxv;
        float y0f = floorf(ys), x0f = floorf(xs);
        int y0 = (int)y0f, x0 = (int)x0f;
        float ly = ys - y0f, lx = xs - x0f;
        float v0y = ((unsigned)y0 < 128u) ? 1.f : 0.f;
        float v1y = ((unsigned)(y0 + 1) < 128u) ? 1.f : 0.f;
        float v0x = ((unsigned)x0 < 128u) ? 1.f : 0.f;
        float v1x = ((unsigned)(x0 + 1) < 128u) ? 1.f : 0.f;
        float w00 = (1.f - ly) * (1.f - lx) * v0y * v0x * m;
        float w01 = (1.f - ly) * lx * v0y * v1x * m;
        float w10 = ly * (1.f - lx) * v1y * v0x * m;
        float w11 = ly * lx * v1y * v1x * m;
        int ly0 = y0 - base_y, lx0 = x0 - base_x;
        bool inp = ((unsigned)ly0 < 12u) && ((unsigned)lx0 < 18u);

        // ---- BRANCHLESS common path: always read LDS at clamped in-patch base ----
        int ly0c = min(max(ly0, 0), 11);
        int lx0c = min(max(lx0, 0), 17);
        int pb = qbase + (ly0c * 20 + lx0c) * 8;     // corners = imm offsets off one base
        uint4 r[2][4];
#pragma unroll
        for (int kb = 0; kb < 2; ++kb) {
            int base = pb + kb * 4 * PSTR;           // kb term folds to imm in ds_read
            r[kb][0] = *(const uint4*)&patch[base];
            r[kb][1] = *(const uint4*)&patch[base + 8];
            r[kb][2] = *(const uint4*)&patch[base + 160];
            r[kb][3] = *(const uint4*)&patch[base + 168];
        }
        if (__any(!inp)) {   // rare wave-level fixup: overwrite from global, clamped corners
            if (!inp) {
                int y0c = min(max(y0, 0), 127), y1c = min(max(y0 + 1, 0), 127);
                int x0c = min(max(x0, 0), 127), x1c = min(max(x0 + 1, 0), 127);
                int base00 = (y0c * 128 + x0c) * 64;
                int dxo = (x1c - x0c) * 64, dyo = (y1c - y0c) * 8192;
#pragma unroll
                for (int kb = 0; kb < 2; ++kb) {
                    int c0 = kb * 32 + quad * 8;
                    r[kb][0] = *(const uint4*)&xbb[base00 + c0];
                    r[kb][1] = *(const uint4*)&xbb[base00 + dxo + c0];
                    r[kb][2] = *(const uint4*)&xbb[base00 + dyo + c0];
                    r[kb][3] = *(const uint4*)&xbb[base00 + dyo + dxo + c0];
                }
            }
        }

        // packed-f16 bilinear: 2 channels per step; pure v_pk_mul/fma_f16, no unpack/repack
        __half2 W00 = __float2half2_rn(w00), W01 = __float2half2_rn(w01);
        __half2 W10 = __float2half2_rn(w10), W11 = __float2half2_rn(w11);
        f16x8 af[2];
#pragma unroll
        for (int kb = 0; kb < 2; ++kb) {
            union { unsigned u[4]; f16x8 f; } afu;
#pragma unroll
            for (int p = 0; p < 4; ++p) {
                __half2 v = __hmul2(W00, u2h2(uget(r[kb][0], p)));
                v = __hfma2(W01, u2h2(uget(r[kb][1], p)), v);
                v = __hfma2(W10, u2h2(uget(r[kb][2], p)), v);
                v = __hfma2(W11, u2h2(uget(r[kb][3], p)), v);
                afu.u[p] = h22u(v);
            }
            af[kb] = afu.f;
        }

#pragma unroll
        for (int kb = 0; kb < 2; ++kb)
#pragma unroll
            for (int nt = 0; nt < 4; ++nt)
                acc[nt] = __builtin_amdgcn_mfma_f32_16x16x32_f16(af[kb], s2f(bfr[kb][nt]), acc[nt], 0, 0, 0);
    }

    // ---- epilogue: lane's 4 D-rows per nt = row w, cols quad*4..+3 -> float4 ----
    int ehh = h0 + w, eww = w0 + quad * 4;
#pragma unroll
    for (int nt = 0; nt < 4; ++nt) {
        int o = nt * 16 + ln;
        float bo = bias[o];
        float4 v;
        v.x = acc[nt][0] + bo; v.y = acc[nt][1] + bo;
        v.z = acc[nt][2] + bo; v.w = acc[nt][3] + bo;
        *(float4*)&out[((size_t)b * 64 + o) * 16384 + ehh * 128 + eww] = v;
    }
}

extern "C" void kernel_launch(void* const* d_in, const int* in_sizes, int n_in,
                              void* d_out, int out_size, void* d_ws, size_t ws_size,
                              hipStream_t stream) {
    const float* x      = (const float*)d_in[0];
    const float* weight = (const float*)d_in[1];
    const float* bias   = (const float*)d_in[2];
    const float* pg_w   = (const float*)d_in[3];
    const float* pg_b   = (const float*)d_in[4];
    float* out = (float*)d_out;

    unsigned short* xhB  = (unsigned short*)d_ws;        // 4*16384*64 f16 (8.39 MB)
    unsigned short* wtF  = xhB + (size_t)4 * 16384 * 64; // 36,864 f16 (fragment order)
    unsigned short* pgwF = wtF + 36864;                  // 18,432 f16 (fragment order)

    k_prep<<<2264, 256, 0, stream>>>(x, xhB, weight, pg_w, wtF, pgwF);
    k_fused<<<512, 512, 0, stream>>>(xhB, pgwF, pg_b, wtF, bias, out);
}

// Round 11
// 97.532 us; speedup vs baseline: 1.1856x; 1.0100x over previous
//
#include <hip/hip_runtime.h>
#include <hip/hip_fp16.h>
#include <math.h>

// B=4, C=64, H=W=128, O=64, K=3, pad=1, stride=1
// Round-24: R17 base (green 97.2us; R18/R23 unroll+branchless were neutral->reverted)
// + ONE delta: EXPLICIT 1-deep software pipeline in phase 2 at kb granularity.
// Two named corner-register sets rA/rB (static indexing): issue kb=1 reads while
// converting kb=0; compute params(kk+1) + issue its kb=0 reads while converting kb=1.
// Corner ds_read latency (~120cy) hides under the other half's cvt+MFMA (~100cy).
// Evidence: R21 counters (k_fused all pipes <30% busy; LDS~7us VALU~7us MFMA~3us of
// ~26us) => unoverlapped latency; compiler-side fixes (unroll R18, branchless R23)
// both null => pipeline by hand. Runtime kk loop (unroll measured negative).
// __launch_bounds__(512,4) caps VGPR<=128 -> keeps 2 blocks/CU.
// Known harness floor ~64us (268MB ws re-poison fill + restores) is inside dur_us.
// ws: xh 8.39 MB + wtF + pgwF (~8.5 MB)

typedef __attribute__((ext_vector_type(8))) short short8;     // 8 f16 bit-patterns (A/B frag)
typedef __attribute__((ext_vector_type(8))) _Float16 f16x8;   // MFMA A/B frag (4 VGPRs)
typedef __attribute__((ext_vector_type(4))) float f32x4;      // C/D frag

#define PSTR 2088   // padded plane stride in shorts (260 pos * 8 ch + 8 pad)

__device__ __forceinline__ unsigned short f2h(float f) {   // RNE f32->f16
    union { __half h; unsigned short s; } v; v.h = __float2half_rn(f); return v.s;
}
__device__ __forceinline__ f16x8 s2f(short8 s) {
    union { short8 s; f16x8 f; } u; u.s = s; return u.f;
}
__device__ __forceinline__ __half2 u2h2(unsigned u) {
    union { unsigned u; __half2 h; } v; v.u = u; return v.h;
}
__device__ __forceinline__ unsigned uget(const uint4& v, int p) {
    return p == 0 ? v.x : p == 1 ? v.y : p == 2 ? v.z : v.w;
}

// ---------------- K0: merged prep: NCHW->NHWC f16 transpose  +  weight pack (exact R17) ----------------
__global__ __launch_bounds__(256) void k_prep(const float* __restrict__ x,
                                              unsigned short* __restrict__ xh,
                                              const float* __restrict__ weight,
                                              const float* __restrict__ pg_w,
                                              unsigned short* __restrict__ wtF,
                                              unsigned short* __restrict__ pgwF) {
    __shared__ float tile[64][33];
    int bid = blockIdx.x;
    int t = threadIdx.x;
    if (bid < 2048) {
        int b = bid >> 9, h = (bid >> 2) & 127, w0 = (bid & 3) * 32;
        for (int idx = t; idx < 2048; idx += 256) {
            int c = idx >> 5, w = idx & 31;
            tile[c][w] = x[((b * 64 + c) * 128 + h) * 128 + w0 + w];
        }
        __syncthreads();
        {
            int wl = t >> 3, c0 = (t & 7) * 8;
            short8 v;
#pragma unroll
            for (int e = 0; e < 8; ++e) v[e] = (short)f2h(tile[c0 + e][wl]);
            *(short8*)&xh[(((size_t)b * 128 + h) * 128 + w0 + wl) * 64 + c0] = v;
        }
    } else {
        int idx = (bid - 2048) * 256 + t;
        if (idx < 36864) {
            int e = idx & 7, l = (idx >> 3) & 63, grp = idx >> 9;   // grp 0..71
            int nt = grp & 3, kb = (grp >> 2) & 1, kk = grp >> 3;
            int ln = l & 15, quad = l >> 4;
            int o = nt * 16 + ln;
            int c = kb * 32 + quad * 8 + e;
            wtF[idx] = f2h(weight[(o * 64 + c) * 9 + kk]);
        }
        int i2 = idx - 36864;
        if (i2 >= 0 && i2 < 18432) {
            int e = i2 & 7, l = (i2 >> 3) & 63, grp = i2 >> 9;      // grp 0..35
            int tl = grp & 1, kb = grp >> 1;
            int ln = l & 15, quad = l >> 4;
            int p = tl * 16 + ln;
            int k = kb * 32 + quad * 8 + e;
            float v = 0.f;
            if (p < 27) {
                int q = k >> 6, c = k & 63;
                v = pg_w[(p * 64 + c) * 9 + q];
            }
            pgwF[i2] = f2h(v);
        }
    }
}

// ---- phase-2 helper macros (all static indexing; bodies verbatim-derived from R17) ----
#define PARAMS(KK, W00_, W01_, W10_, W11_, PB_, INP_, Y0_, X0_)                   \
    {                                                                             \
        int ki_ = (KK) / 3, kj_ = (KK) - 3 * ((KK) / 3);                          \
        float dyv_ = P_s[(2 * (KK)) * 129 + px];                                  \
        float dxv_ = P_s[(2 * (KK) + 1) * 129 + px];                              \
        float mm_  = P_s[(18 + (KK)) * 129 + px];                                 \
        float ys_ = (float)(hh - 1 + ki_) + dyv_;                                 \
        float xs_ = (float)(ww - 1 + kj_) + dxv_;                                 \
        float y0f_ = floorf(ys_), x0f_ = floorf(xs_);                             \
        int y0_ = (int)y0f_, x0_ = (int)x0f_;                                     \
        float ly_ = ys_ - y0f_, lx_ = xs_ - x0f_;                                 \
        float v0y_ = ((unsigned)y0_ < 128u) ? 1.f : 0.f;                          \
        float v1y_ = ((unsigned)(y0_ + 1) < 128u) ? 1.f : 0.f;                    \
        float v0x_ = ((unsigned)x0_ < 128u) ? 1.f : 0.f;                          \
        float v1x_ = ((unsigned)(x0_ + 1) < 128u) ? 1.f : 0.f;                    \
        W00_ = __float2half2_rn((1.f - ly_) * (1.f - lx_) * v0y_ * v0x_ * mm_);   \
        W01_ = __float2half2_rn((1.f - ly_) * lx_ * v0y_ * v1x_ * mm_);           \
        W10_ = __float2half2_rn(ly_ * (1.f - lx_) * v1y_ * v0x_ * mm_);           \
        W11_ = __float2half2_rn(ly_ * lx_ * v1y_ * v1x_ * mm_);                   \
        int ly0_ = y0_ - base_y, lx0_ = x0_ - base_x;                             \
        INP_ = ((unsigned)ly0_ < 12u) && ((unsigned)lx0_ < 18u);                  \
        int ly0c_ = min(max(ly0_, 0), 11), lx0c_ = min(max(lx0_, 0), 17);         \
        PB_ = qbase + (ly0c_ * 20 + lx0c_) * 8;                                   \
        Y0_ = y0_; X0_ = x0_;                                                     \
    }

#define RD4(DST, BASE)                                                            \
    { DST[0] = *(const uint4*)&patch[(BASE)];                                     \
      DST[1] = *(const uint4*)&patch[(BASE) + 8];                                 \
      DST[2] = *(const uint4*)&patch[(BASE) + 160];                               \
      DST[3] = *(const uint4*)&patch[(BASE) + 168]; }

#define FIX(DST, KB, INP, Y0, X0)                                                 \
    if (__any(!(INP))) { if (!(INP)) {                                            \
        int y0c_ = min(max((Y0), 0), 127), y1c_ = min(max((Y0) + 1, 0), 127);     \
        int x0c_ = min(max((X0), 0), 127), x1c_ = min(max((X0) + 1, 0), 127);     \
        int b00_ = (y0c_ * 128 + x0c_) * 64;                                      \
        int dxo_ = (x1c_ - x0c_) * 64, dyo_ = (y1c_ - y0c_) * 8192;               \
        int c0_ = (KB) * 32 + quad * 8;                                           \
        DST[0] = *(const uint4*)&xbb[b00_ + c0_];                                 \
        DST[1] = *(const uint4*)&xbb[b00_ + dxo_ + c0_];                          \
        DST[2] = *(const uint4*)&xbb[b00_ + dyo_ + c0_];                          \
        DST[3] = *(const uint4*)&xbb[b00_ + dyo_ + dxo_ + c0_]; } }

#define CVTMMA(RSET, KK, KB, W00_, W01_, W10_, W11_)                              \
    {                                                                             \
        short8 bfr_[4];                                                           \
        _Pragma("unroll")                                                         \
        for (int nt = 0; nt < 4; ++nt)                                            \
            bfr_[nt] = *(const short8*)&wtF[(((KK) * 2 + (KB)) * 4 + nt) * 512 + l * 8]; \
        union { unsigned u[4]; f16x8 f; } afu_;                                   \
        _Pragma("unroll")                                                         \
        for (int p = 0; p < 4; ++p) {                                             \
            __half2 v_ = __hmul2(W00_, u2h2(uget(RSET[0], p)));                   \
            v_ = __hfma2(W01_, u2h2(uget(RSET[1], p)), v_);                       \
            v_ = __hfma2(W10_, u2h2(uget(RSET[2], p)), v_);                       \
            v_ = __hfma2(W11_, u2h2(uget(RSET[3], p)), v_);                       \
            afu_.u[p] = *(unsigned*)&v_;                                          \
        }                                                                         \
        _Pragma("unroll")                                                         \
        for (int nt = 0; nt < 4; ++nt)                                            \
            acc[nt] = __builtin_amdgcn_mfma_f32_16x16x32_f16(afu_.f, s2f(bfr_[nt]), acc[nt], 0, 0, 0); \
    }

// ---------------- K2: fused offset-conv + deformable conv, 8x16 tile ----------------
// 512 blocks (b x 16 x 8), tile = 8 rows x 16 cols. 512 threads = 8 waves; wave w = row w.
__global__ __launch_bounds__(512, 4) void k_fused(const unsigned short* __restrict__ xh,
                                                  const unsigned short* __restrict__ pgwF,
                                                  const float* __restrict__ pg_b,
                                                  const unsigned short* __restrict__ wtF,
                                                  const float* __restrict__ bias,
                                                  float* __restrict__ out) {
    __shared__ unsigned short patch[8 * PSTR];   // 32.6 KB [cg][pos][8ch], plane pad +8
    __shared__ float P_s[27 * 129];              // 13.9 KB [param][px], stride 129

    int bid = blockIdx.x;
    int b  = bid >> 7;
    int h0 = ((bid >> 3) & 15) * 8;
    int w0 = (bid & 7) * 16;
    int t = threadIdx.x;
    int base_y = h0 - 2, base_x = w0 - 2;
    const unsigned short* xbb = xh + (size_t)b * 16384 * 64;

    // ---- phase 0: stage patch from xh; 2080 b128 chunks, coalesced ----
    for (int i = t; i < 2080; i += 512) {
        int yy = i / 160;                 // 8 chunks per 20-col row
        int r  = i - yy * 160;
        int xx = r >> 3;
        int cg = r & 7;
        int gy = base_y + yy, gx = base_x + xx;
        int pos = yy * 20 + xx;
        short8 v = (short8)0;
        if (((unsigned)gy < 128u) && ((unsigned)gx < 128u))
            v = *(const short8*)&xbb[(gy * 128 + gx) * 64 + cg * 8];
        *(short8*)&patch[cg * PSTR + pos * 8] = v;
    }
    __syncthreads();

    int l = t & 63, w = t >> 6;          // w = 0..7 = pixel row
    int quad = l >> 4, ln = l & 15;
    int px = w * 16 + ln;                // px = row-major pixel id (row w, col ln)
    int hh = h0 + w, ww = w0 + ln;

    // ---- phase 1: offset conv MFMA (M=128, N=32, K=576), B from pgwF coalesced ----
    {
        f32x4 o0 = {0.f, 0.f, 0.f, 0.f}, o1 = {0.f, 0.f, 0.f, 0.f};
#pragma unroll
        for (int kb = 0; kb < 18; ++kb) {
            int q = kb >> 1;
            int kh = q / 3, kw = q - 3 * (q / 3);
            short8 b0 = *(const short8*)&pgwF[(kb * 2 + 0) * 512 + l * 8];   // lane*16B
            short8 b1 = *(const short8*)&pgwF[(kb * 2 + 1) * 512 + l * 8];
            int aoff = (w + kh + 1) * 20 + (ln + kw + 1);
            int cg = (kb & 1) * 4 + quad;
            short8 af = *(const short8*)&patch[cg * PSTR + aoff * 8];
            o0 = __builtin_amdgcn_mfma_f32_16x16x32_f16(s2f(af), s2f(b0), o0, 0, 0, 0);
            o1 = __builtin_amdgcn_mfma_f32_16x16x32_f16(s2f(af), s2f(b1), o1, 0, 0, 0);
        }
#pragma unroll
        for (int tile = 0; tile < 2; ++tile) {
            int p = tile * 16 + ln;
            f32x4 a = tile ? o1 : o0;
            if (p < 27) {
                float bo = pg_b[p];
#pragma unroll
                for (int i = 0; i < 4; ++i) {
                    int wpx = w * 16 + quad * 4 + i;
                    float v = a[i] + bo;
                    if (p >= 18) v = 1.f / (1.f + expf(-v));
                    P_s[p * 129 + wpx] = v;
                }
            }
        }
    }
    __syncthreads();

    // ---- phase 2: sampling + main GEMM, explicit 1-deep pipeline at kb granularity ----
    f32x4 acc[4];
#pragma unroll
    for (int nt = 0; nt < 4; ++nt) acc[nt] = (f32x4){0.f, 0.f, 0.f, 0.f};

    int qbase = quad * PSTR;             // per-thread constant plane base

    __half2 W00, W01, W10, W11, nW00, nW01, nW10, nW11;
    int pb, npb, y0c, x0c, ny0, nx0;
    bool inp, ninp;
    uint4 rA[4], rB[4];

    // prologue: params(kk=0) + issue kb=0 corner reads
    PARAMS(0, W00, W01, W10, W11, pb, inp, y0c, x0c);
    RD4(rA, pb);

    for (int kk = 0; kk < 9; ++kk) {
        RD4(rB, pb + 4 * PSTR);                  // issue kb=1 reads (addr known)
        FIX(rA, 0, inp, y0c, x0c);
        CVTMMA(rA, kk, 0, W00, W01, W10, W11);   // convert+MFMA kb=0 (hides rB latency)
        if (kk < 8) {
            PARAMS(kk + 1, nW00, nW01, nW10, nW11, npb, ninp, ny0, nx0);
            RD4(rA, npb);                        // issue next kk's kb=0 reads
        }
        FIX(rB, 1, inp, y0c, x0c);
        CVTMMA(rB, kk, 1, W00, W01, W10, W11);   // convert+MFMA kb=1 (hides rA latency)
        W00 = nW00; W01 = nW01; W10 = nW10; W11 = nW11;
        pb = npb; inp = ninp; y0c = ny0; x0c = nx0;
    }

    // ---- epilogue: lane's 4 D-rows per nt = row w, cols quad*4..+3 -> float4 ----
    int ehh = h0 + w, eww = w0 + quad * 4;
#pragma unroll
    for (int nt = 0; nt < 4; ++nt) {
        int o = nt * 16 + ln;
        float bo = bias[o];
        float4 v;
        v.x = acc[nt][0] + bo; v.y = acc[nt][1] + bo;
        v.z = acc[nt][2] + bo; v.w = acc[nt][3] + bo;
        *(float4*)&out[((size_t)b * 64 + o) * 16384 + ehh * 128 + eww] = v;
    }
}

extern "C" void kernel_launch(void* const* d_in, const int* in_sizes, int n_in,
                              void* d_out, int out_size, void* d_ws, size_t ws_size,
                              hipStream_t stream) {
    const float* x      = (const float*)d_in[0];
    const float* weight = (const float*)d_in[1];
    const float* bias   = (const float*)d_in[2];
    const float* pg_w   = (const float*)d_in[3];
    const float* pg_b   = (const float*)d_in[4];
    float* out = (float*)d_out;

    unsigned short* xhB  = (unsigned short*)d_ws;        // 4*16384*64 f16 (8.39 MB)
    unsigned short* wtF  = xhB + (size_t)4 * 16384 * 64; // 36,864 f16 (fragment order)
    unsigned short* pgwF = wtF + 36864;                  // 18,432 f16 (fragment order)

    k_prep<<<2264, 256, 0, stream>>>(x, xhB, weight, pg_w, wtF, pgwF);
    k_fused<<<512, 512, 0, stream>>>(xhB, pgwF, pg_b, wtF, bias, out);
}